// Round 1
// baseline (389.817 us; speedup 1.0000x reference)
//
#include <hip/hip_runtime.h>
#include <math.h>

#define D    128
#define CCLS 64
#define BT   128
#define BK   32
#define LP   132   // padded LDS row (132*4B stride keeps 16B alignment)

__device__ __forceinline__ float wave_reduce_sum(float v) {
    #pragma unroll
    for (int off = 32; off > 0; off >>= 1) v += __shfl_xor(v, off, 64);
    return v;
}

// --- init: zero accumulators, set cls_freq = 1 + 1e-6 -----------------------
__global__ void init_kernel(float* numer, float* denom, float* cls_freq,
                            float* loss_sum, int M) {
    int i = blockIdx.x * blockDim.x + threadIdx.x;
    if (i < M) { numer[i] = 0.f; denom[i] = 0.f; }
    if (i < CCLS) cls_freq[i] = 1.0f + 1e-6f;
    if (i == 0) loss_sum[0] = 0.f;
}

// --- normalize feats & protos; fold sqrt(log2e/TAU) into the scale;
//     count class frequencies. One wave per row. ----------------------------
__global__ void norm_kernel(const float* __restrict__ protos,
                            const float* __restrict__ proj2,
                            const int* __restrict__ t2,
                            const float* __restrict__ proj3,
                            const int* __restrict__ t3,
                            float* __restrict__ featsN,
                            float* __restrict__ protosN,
                            float* cls_freq, int N, int M) {
    const float SCL = sqrtf(1.44269504088896340736f * 10.0f); // sqrt(log2e / TAU)
    int w = threadIdx.x >> 6;
    int lane = threadIdx.x & 63;
    int row = blockIdx.x * (blockDim.x >> 6) + w;
    if (row >= M + CCLS) return;
    const float* src;
    float* dst;
    if (row < M) {
        src = (row < N) ? (proj2 + (size_t)row * D) : (proj3 + (size_t)(row - N) * D);
        dst = featsN + (size_t)row * D;
    } else {
        src = protos + (size_t)(row - M) * D;
        dst = protosN + (size_t)(row - M) * D;
    }
    float2 v = ((const float2*)src)[lane];
    float ss = wave_reduce_sum(v.x * v.x + v.y * v.y);
    float scale = SCL / fmaxf(sqrtf(ss), 1e-12f);
    float2 o = { v.x * scale, v.y * scale };
    ((float2*)dst)[lane] = o;
    if (row < M && lane == 0) {
        int lab = (row < N) ? t2[row] : t3[row - N];
        atomicAdd(&cls_freq[lab], 1.0f);
    }
}

// --- main: 128x128 tile per block, 8x8 micro-tile per thread, fused
//     exp2 + diag mask + label match + row-sum epilogue. --------------------
__global__ __launch_bounds__(256)
void sim_kernel(const float* __restrict__ featsN,
                const int* __restrict__ t2, const int* __restrict__ t3,
                float* __restrict__ numer_region, float* __restrict__ denom_region,
                int N, int M) {
    __shared__ float As[BK][LP];   // transposed: As[k][r]
    __shared__ float Bs[BK][LP];
    __shared__ int   rlab[BT];
    __shared__ int   clab[BT];

    const int t = threadIdx.x;
    const int bi = blockIdx.x, bj = blockIdx.y;
    const int rowBase = bi * BT, colBase = bj * BT;

    if (t < BT) {
        int gi = rowBase + t;
        rlab[t] = (gi < N) ? t2[gi] : t3[gi - N];
    } else {
        int gj = colBase + (t - BT);
        clab[t - BT] = (gj < N) ? t2[gj] : t3[gj - N];
    }

    const int tc = t & 15;       // 0..15 -> 8 cols each
    const int tr = t >> 4;       // 0..15 -> 8 rows each
    const int lr  = t >> 3;      // staging: row 0..31
    const int lkq = t & 7;       // staging: k-quad 0..7

    float acc[8][8];
    #pragma unroll
    for (int i = 0; i < 8; ++i)
        #pragma unroll
        for (int j = 0; j < 8; ++j) acc[i][j] = 0.f;

    for (int kt = 0; kt < D; kt += BK) {
        __syncthreads();
        #pragma unroll
        for (int q = 0; q < 4; ++q) {
            int r = lr + 32 * q;
            float4 a = *(const float4*)&featsN[(size_t)(rowBase + r) * D + kt + lkq * 4];
            As[lkq * 4 + 0][r] = a.x; As[lkq * 4 + 1][r] = a.y;
            As[lkq * 4 + 2][r] = a.z; As[lkq * 4 + 3][r] = a.w;
            float4 b = *(const float4*)&featsN[(size_t)(colBase + r) * D + kt + lkq * 4];
            Bs[lkq * 4 + 0][r] = b.x; Bs[lkq * 4 + 1][r] = b.y;
            Bs[lkq * 4 + 2][r] = b.z; Bs[lkq * 4 + 3][r] = b.w;
        }
        __syncthreads();
        #pragma unroll 2
        for (int k = 0; k < BK; ++k) {
            float4 a0 = *(const float4*)&As[k][tr * 8];
            float4 a1 = *(const float4*)&As[k][tr * 8 + 4];
            float4 b0 = *(const float4*)&Bs[k][tc * 8];
            float4 b1 = *(const float4*)&Bs[k][tc * 8 + 4];
            float av[8] = {a0.x, a0.y, a0.z, a0.w, a1.x, a1.y, a1.z, a1.w};
            float bv[8] = {b0.x, b0.y, b0.z, b0.w, b1.x, b1.y, b1.z, b1.w};
            #pragma unroll
            for (int i = 0; i < 8; ++i)
                #pragma unroll
                for (int j = 0; j < 8; ++j)
                    acc[i][j] = fmaf(av[i], bv[j], acc[i][j]);
        }
    }

    // epilogue: exp2, diag mask, label match, per-row sums
    #pragma unroll
    for (int i = 0; i < 8; ++i) {
        int gi = rowBase + tr * 8 + i;
        int rl = rlab[tr * 8 + i];
        float rn = 0.f, rd = 0.f;
        #pragma unroll
        for (int j = 0; j < 8; ++j) {
            int gj = colBase + tc * 8 + j;
            float e = (gi == gj) ? 0.f : exp2f(acc[i][j]);
            rd += e;
            if (rl == clab[tc * 8 + j]) rn += e;
        }
        #pragma unroll
        for (int off = 1; off < 16; off <<= 1) {
            rn += __shfl_xor(rn, off, 64);
            rd += __shfl_xor(rd, off, 64);
        }
        if (tc == 0) {
            atomicAdd(&numer_region[gi], rn);
            atomicAdd(&denom_region[gi], rd);
        }
    }
}

// --- finalize: proto terms + per-row loss. One wave per row, lane = proto. --
__global__ void fin_kernel(const float* __restrict__ featsN,
                           const float* __restrict__ protosN,
                           const int* __restrict__ t2, const int* __restrict__ t3,
                           const float* __restrict__ cls_freq,
                           const float* __restrict__ numer_region,
                           const float* __restrict__ denom_region,
                           float* loss_sum, int N, int M) {
    int w = threadIdx.x >> 6;
    int lane = threadIdx.x & 63;
    int i = blockIdx.x * (blockDim.x >> 6) + w;
    if (i >= M) return;
    const float* f = featsN + (size_t)i * D;
    const float* p = protosN + (size_t)lane * D;
    float acc = 0.f;
    #pragma unroll
    for (int k = 0; k < D / 4; ++k) {
        float4 fa = ((const float4*)f)[k];
        float4 pa = ((const float4*)p)[k];
        acc += fa.x * pa.x + fa.y * pa.y + fa.z * pa.z + fa.w * pa.w;
    }
    float ep = exp2f(acc);                  // exp(proto_sim / TAU)
    float dp = ep / cls_freq[lane];
    float dsum = wave_reduce_sum(dp);
    int lab = (i < N) ? t2[i] : t3[i - N];
    float ep_lab = __shfl(ep, lab, 64);
    float numer = numer_region[i] + ep_lab;
    float denom = denom_region[i] / cls_freq[lab] + dsum;
    float loss = logf(denom + 1e-12f) - logf(numer);
    if (lane == 0) atomicAdd(loss_sum, loss);
}

__global__ void out_kernel(const float* loss_sum, float* out, int M) {
    out[0] = loss_sum[0] / (float)M;
}

extern "C" void kernel_launch(void* const* d_in, const int* in_sizes, int n_in,
                              void* d_out, int out_size, void* d_ws, size_t ws_size,
                              hipStream_t stream) {
    const float* protos = (const float*)d_in[0];
    const float* proj2  = (const float*)d_in[1];
    const int*   t2     = (const int*)d_in[2];
    const float* proj3  = (const float*)d_in[3];
    const int*   t3     = (const int*)d_in[4];
    float* out = (float*)d_out;

    const int N = in_sizes[1] / D;   // 4096
    const int M = 2 * N;             // 8192

    float* ws = (float*)d_ws;
    float* featsN       = ws;                                // M*D
    float* protosN      = featsN + (size_t)M * D;            // CCLS*D
    float* cls_freq     = protosN + (size_t)CCLS * D;        // CCLS
    float* numer_region = cls_freq + CCLS;                   // M
    float* denom_region = numer_region + M;                  // M
    float* loss_sum     = denom_region + M;                  // 1

    init_kernel<<<(M + 255) / 256, 256, 0, stream>>>(numer_region, denom_region,
                                                     cls_freq, loss_sum, M);
    norm_kernel<<<(M + CCLS + 3) / 4, 256, 0, stream>>>(protos, proj2, t2, proj3, t3,
                                                        featsN, protosN, cls_freq, N, M);
    dim3 grid(M / BT, M / BT);
    sim_kernel<<<grid, 256, 0, stream>>>(featsN, t2, t3, numer_region, denom_region, N, M);
    fin_kernel<<<(M + 3) / 4, 256, 0, stream>>>(featsN, protosN, t2, t3, cls_freq,
                                                numer_region, denom_region, loss_sum, N, M);
    out_kernel<<<1, 1, 0, stream>>>(loss_sum, out, M);
}

// Round 2
// 111.698 us; speedup vs baseline: 3.4899x; 3.4899x over previous
//
#include <hip/hip_runtime.h>
#include <math.h>

#define D    128
#define CCLS 64

typedef _Float16 f16x8 __attribute__((ext_vector_type(8)));
typedef _Float16 f16x2 __attribute__((ext_vector_type(2)));
typedef float    f32x4 __attribute__((ext_vector_type(4)));

__device__ __forceinline__ float wave_reduce_sum(float v) {
    #pragma unroll
    for (int off = 32; off > 0; off >>= 1) v += __shfl_xor(v, off, 64);
    return v;
}

// --- init: zero accumulators, cls_freq = 1 + 1e-6 ---------------------------
__global__ void init_kernel(float* numer, float* denomR, float* denomP,
                            float* cls_freq, float* loss_sum, int M) {
    int i = blockIdx.x * blockDim.x + threadIdx.x;
    if (i < M) { numer[i] = 0.f; denomR[i] = 0.f; denomP[i] = 0.f; }
    if (i < CCLS) cls_freq[i] = 1.0f + 1e-6f;
    if (i == 0) loss_sum[0] = 0.f;
}

// --- normalize rows (feats ++ protos ++ zero-pad), fold sqrt(log2e/TAU),
//     cast to f16, write MFMA-tiled layout: elem(r,k) ->
//     ((r>>4)*16 + (k>>3))*128 + (r&15)*8 + (k&7).  One wave per row. -------
__global__ void norm_kernel(const float* __restrict__ protos,
                            const float* __restrict__ proj2,
                            const int* __restrict__ t2,
                            const float* __restrict__ proj3,
                            const int* __restrict__ t3,
                            _Float16* __restrict__ ftile,
                            float* cls_freq, int N, int M) {
    const float SCL = 3.8017368953f;  // sqrt(10 * log2(e))
    int w = threadIdx.x >> 6;
    int lane = threadIdx.x & 63;
    int row = blockIdx.x * (blockDim.x >> 6) + w;
    const int MT = M + 128;           // feats + protos + zero-pad
    if (row >= MT) return;
    const float* src = nullptr;
    if (row < M)            src = (row < N) ? proj2 + (size_t)row * D
                                            : proj3 + (size_t)(row - N) * D;
    else if (row < M + CCLS) src = protos + (size_t)(row - M) * D;
    float2 v = {0.f, 0.f};
    if (src) v = ((const float2*)src)[lane];
    float ss = wave_reduce_sum(v.x * v.x + v.y * v.y);
    float scale = src ? SCL / fmaxf(sqrtf(ss), 1e-12f) : 0.f;
    f16x2 h = { (_Float16)(v.x * scale), (_Float16)(v.y * scale) };
    int k0 = 2 * lane;
    size_t off = ((size_t)(row >> 4) * 16 + (k0 >> 3)) * 128 + (row & 15) * 8 + (k0 & 7);
    *(f16x2*)(ftile + off) = h;
    if (row < M && lane == 0) {
        int lab = (row < N) ? t2[row] : t3[row - N];
        atomicAdd(&cls_freq[lab], 1.0f);
    }
}

// --- main GEMM: 128x128 output tile, 4 waves of 64x64, mfma_f32_16x16x32_f16,
//     fragments loaded straight from the L2-resident tiled table (no LDS
//     operand staging, no K-loop barriers). bj==gridDim.y-1 is the proto
//     column block (weights 1/cls_freq, zero-padded cols masked by weight 0).
__global__ __launch_bounds__(256)
void sim_kernel(const _Float16* __restrict__ ftile,
                const int* __restrict__ t2, const int* __restrict__ t3,
                const float* __restrict__ cls_freq,
                float* __restrict__ numer, float* __restrict__ denomR,
                float* __restrict__ denomP, int N, int M) {
    __shared__ int   rlab[128];
    __shared__ int   clab[128];
    __shared__ float cw[128];
    __shared__ float rowNs[2][128];
    __shared__ float rowDs[2][128];

    const int t = threadIdx.x;
    const int bi = blockIdx.x, bj = blockIdx.y;
    const int rowBase = bi * 128;
    const bool isProto = (bj == (int)gridDim.y - 1);
    const int colBase = bj * 128;

    if (t < 128) {
        int gi = rowBase + t;
        rlab[t] = (gi < N) ? t2[gi] : t3[gi - N];
        if (!isProto) {
            int gj = colBase + t;
            clab[t] = (gj < N) ? t2[gj] : t3[gj - N];
            cw[t] = 1.f;
        } else {
            clab[t] = (t < CCLS) ? t : -1;
            cw[t]   = (t < CCLS) ? 1.f / cls_freq[t] : 0.f;
        }
    }
    __syncthreads();

    const int w = t >> 6, lane = t & 63;
    const int wr = (w >> 1) * 64, wc = (w & 1) * 64;
    const int rtA = (rowBase + wr) >> 4;
    const int rtB = ((isProto ? M : colBase) + wc) >> 4;
    const int lo  = (lane >> 4) * 128 + (lane & 15) * 8;

    f32x4 acc[4][4];
    #pragma unroll
    for (int m = 0; m < 4; ++m)
        #pragma unroll
        for (int n = 0; n < 4; ++n)
            #pragma unroll
            for (int r = 0; r < 4; ++r) acc[m][n][r] = 0.f;

    #pragma unroll
    for (int kt = 0; kt < 4; ++kt) {
        f16x8 a[4], b[4];
        #pragma unroll
        for (int m = 0; m < 4; ++m)
            a[m] = *(const f16x8*)(ftile + (size_t)(rtA + m) * 2048 + kt * 512 + lo);
        #pragma unroll
        for (int n = 0; n < 4; ++n)
            b[n] = *(const f16x8*)(ftile + (size_t)(rtB + n) * 2048 + kt * 512 + lo);
        #pragma unroll
        for (int m = 0; m < 4; ++m)
            #pragma unroll
            for (int n = 0; n < 4; ++n)
                acc[m][n] = __builtin_amdgcn_mfma_f32_16x16x32_f16(a[m], b[n], acc[m][n], 0, 0, 0);
    }

    // epilogue: exp2 + diag mask + label match + per-row sums.
    // C layout: col = lane&15, row = (lane>>4)*4 + reg.
    const bool diag = (!isProto) && (bi == bj);
    float* __restrict__ dD = isProto ? denomP : denomR;

    #pragma unroll
    for (int m = 0; m < 4; ++m) {
        const int rbase = wr + m * 16 + (lane >> 4) * 4;
        float rn[4] = {0.f, 0.f, 0.f, 0.f};
        float rd[4] = {0.f, 0.f, 0.f, 0.f};
        #pragma unroll
        for (int n = 0; n < 4; ++n) {
            const int c = wc + n * 16 + (lane & 15);
            const int cl = clab[c];
            const float w_ = cw[c];
            #pragma unroll
            for (int r = 0; r < 4; ++r) {
                const int rr = rbase + r;
                float e = exp2f(acc[m][n][r]);
                if (diag && rr == c) e = 0.f;
                rd[r] += e * w_;
                if (cl == rlab[rr]) rn[r] += e;
            }
        }
        #pragma unroll
        for (int r = 0; r < 4; ++r) {
            #pragma unroll
            for (int off = 1; off < 16; off <<= 1) {
                rn[r] += __shfl_xor(rn[r], off, 64);
                rd[r] += __shfl_xor(rd[r], off, 64);
            }
        }
        if ((lane & 15) == 0) {
            #pragma unroll
            for (int r = 0; r < 4; ++r) {
                rowNs[w & 1][rbase + r] = rn[r];
                rowDs[w & 1][rbase + r] = rd[r];
            }
        }
    }
    __syncthreads();
    if (t < 128) {
        atomicAdd(&numer[rowBase + t], rowNs[0][t] + rowNs[1][t]);
        atomicAdd(&dD[rowBase + t],    rowDs[0][t] + rowDs[1][t]);
    }
}

// --- finalize: elementwise loss + mean --------------------------------------
__global__ void fin_kernel(const int* __restrict__ t2, const int* __restrict__ t3,
                           const float* __restrict__ cls_freq,
                           const float* __restrict__ numer,
                           const float* __restrict__ denomR,
                           const float* __restrict__ denomP,
                           float* loss_sum, int N, int M) {
    int i = blockIdx.x * blockDim.x + threadIdx.x;
    float loss = 0.f;
    if (i < M) {
        int lab = (i < N) ? t2[i] : t3[i - N];
        float denom = denomR[i] / cls_freq[lab] + denomP[i];
        loss = logf(denom + 1e-12f) - logf(numer[i]);
    }
    loss = wave_reduce_sum(loss);
    __shared__ float wsum[4];
    if ((threadIdx.x & 63) == 0) wsum[threadIdx.x >> 6] = loss;
    __syncthreads();
    if (threadIdx.x == 0)
        atomicAdd(loss_sum, wsum[0] + wsum[1] + wsum[2] + wsum[3]);
}

__global__ void out_kernel(const float* loss_sum, float* out, int M) {
    out[0] = loss_sum[0] / (float)M;
}

extern "C" void kernel_launch(void* const* d_in, const int* in_sizes, int n_in,
                              void* d_out, int out_size, void* d_ws, size_t ws_size,
                              hipStream_t stream) {
    const float* protos = (const float*)d_in[0];
    const float* proj2  = (const float*)d_in[1];
    const int*   t2     = (const int*)d_in[2];
    const float* proj3  = (const float*)d_in[3];
    const int*   t3     = (const int*)d_in[4];
    float* out = (float*)d_out;

    const int N = in_sizes[1] / D;   // 4096
    const int M = 2 * N;             // 8192
    const int MT = M + 128;

    _Float16* ftile = (_Float16*)d_ws;                        // MT * D halfs
    float* fbase    = (float*)(ftile + (size_t)MT * D);
    float* cls_freq = fbase;                                  // CCLS
    float* numer    = cls_freq + CCLS;                        // M
    float* denomR   = numer + M;                              // M
    float* denomP   = denomR + M;                             // M
    float* loss_sum = denomP + M;                             // 1

    init_kernel<<<(M + 255) / 256, 256, 0, stream>>>(numer, denomR, denomP,
                                                     cls_freq, loss_sum, M);
    norm_kernel<<<(MT + 3) / 4, 256, 0, stream>>>(protos, proj2, t2, proj3, t3,
                                                  ftile, cls_freq, N, M);
    dim3 grid(M / 128, M / 128 + 1);
    sim_kernel<<<grid, 256, 0, stream>>>(ftile, t2, t3, cls_freq,
                                         numer, denomR, denomP, N, M);
    fin_kernel<<<(M + 255) / 256, 256, 0, stream>>>(t2, t3, cls_freq, numer,
                                                    denomR, denomP, loss_sum, N, M);
    out_kernel<<<1, 1, 0, stream>>>(loss_sum, out, M);
}

// Round 3
// 57.872 us; speedup vs baseline: 6.7358x; 1.9301x over previous
//
#include <hip/hip_runtime.h>
#include <math.h>

#define D    128
#define CCLS 64

typedef _Float16 f16x8 __attribute__((ext_vector_type(8)));
typedef _Float16 f16x2 __attribute__((ext_vector_type(2)));
typedef float    f32x4 __attribute__((ext_vector_type(4)));

__device__ __forceinline__ float wave_reduce_sum(float v) {
    #pragma unroll
    for (int off = 32; off > 0; off >>= 1) v += __shfl_xor(v, off, 64);
    return v;
}

// --- init: zero accumulators ------------------------------------------------
__global__ void init_kernel(float* numer, float* denomR, float* denomP,
                            float* loss_sum, int M) {
    int i = blockIdx.x * blockDim.x + threadIdx.x;
    if (i < M) { numer[i] = 0.f; denomR[i] = 0.f; denomP[i] = 0.f; }
    if (i == 0) loss_sum[0] = 0.f;
}

// --- class histogram: ONE block, LDS atomics only ---------------------------
__global__ void hist_kernel(const int* __restrict__ t2, const int* __restrict__ t3,
                            float* __restrict__ cls_freq, int N, int M) {
    __shared__ int h[CCLS];
    int t = threadIdx.x;
    if (t < CCLS) h[t] = 0;
    __syncthreads();
    for (int i = t; i < M; i += blockDim.x) {
        int lab = (i < N) ? t2[i] : t3[i - N];
        atomicAdd(&h[lab], 1);
    }
    __syncthreads();
    if (t < CCLS) cls_freq[t] = (float)h[t] + 1.0f + 1e-6f;
}

// --- normalize rows (feats ++ protos ++ zero-pad), fold sqrt(log2e/TAU),
//     cast to f16, write MFMA-tiled layout: elem(r,k) ->
//     ((r>>4)*16 + (k>>3))*128 + (r&15)*8 + (k&7).  One wave per row. -------
__global__ void norm_kernel(const float* __restrict__ protos,
                            const float* __restrict__ proj2,
                            const float* __restrict__ proj3,
                            _Float16* __restrict__ ftile, int N, int M) {
    const float SCL = 3.8017368953f;  // sqrt(10 * log2(e))
    int w = threadIdx.x >> 6;
    int lane = threadIdx.x & 63;
    int row = blockIdx.x * (blockDim.x >> 6) + w;
    const int MT = M + 128;           // feats + protos + zero-pad
    if (row >= MT) return;
    const float* src = nullptr;
    if (row < M)            src = (row < N) ? proj2 + (size_t)row * D
                                            : proj3 + (size_t)(row - N) * D;
    else if (row < M + CCLS) src = protos + (size_t)(row - M) * D;
    float2 v = {0.f, 0.f};
    if (src) v = ((const float2*)src)[lane];
    float ss = wave_reduce_sum(v.x * v.x + v.y * v.y);
    float scale = src ? SCL / fmaxf(sqrtf(ss), 1e-12f) : 0.f;
    f16x2 h = { (_Float16)(v.x * scale), (_Float16)(v.y * scale) };
    int k0 = 2 * lane;
    size_t off = ((size_t)(row >> 4) * 16 + (k0 >> 3)) * 128 + (row & 15) * 8 + (k0 & 7);
    *(f16x2*)(ftile + off) = h;
}

// --- main GEMM: 128x128 tile, 4 waves of 64x64, mfma_f32_16x16x32_f16 with
//     SWAPPED operands: acc[m][n] = mfma(b[n], a[m]) so output row index i
//     sits on lane&15 (per-thread constant) and j spans regs -> the per-row
//     sum over j is in-register; only 2 shfl_xor per row at the end. --------
__global__ __launch_bounds__(256)
void sim_kernel(const _Float16* __restrict__ ftile,
                const int* __restrict__ t2, const int* __restrict__ t3,
                const float* __restrict__ cls_freq,
                float* __restrict__ numer, float* __restrict__ denomR,
                float* __restrict__ denomP, int N, int M) {
    __shared__ int   rlab[128];
    __shared__ int   clab[128];
    __shared__ float cw[128];
    __shared__ float rowNs[2][128];
    __shared__ float rowDs[2][128];

    const int t = threadIdx.x;
    const int bi = blockIdx.x, bj = blockIdx.y;
    const int rowBase = bi * 128;
    const bool isProto = (bj == (int)gridDim.y - 1);
    const int colBase = bj * 128;

    if (t < 128) {
        int gi = rowBase + t;
        rlab[t] = (gi < N) ? t2[gi] : t3[gi - N];
        if (!isProto) {
            int gj = colBase + t;
            clab[t] = (gj < N) ? t2[gj] : t3[gj - N];
        } else {
            clab[t] = (t < CCLS) ? t : -1;
            cw[t]   = (t < CCLS) ? 1.f / cls_freq[t] : 0.f;
        }
    }
    __syncthreads();

    const int w = t >> 6, lane = t & 63;
    const int wr = (w >> 1) * 64, wc = (w & 1) * 64;
    const int g = lane >> 4, li = lane & 15;
    const int rtA = (rowBase + wr) >> 4;
    const int rtB = ((isProto ? M : colBase) + wc) >> 4;
    const int lo  = g * 128 + li * 8;

    f32x4 acc[4][4];
    #pragma unroll
    for (int m = 0; m < 4; ++m)
        #pragma unroll
        for (int n = 0; n < 4; ++n)
            #pragma unroll
            for (int r = 0; r < 4; ++r) acc[m][n][r] = 0.f;

    #pragma unroll
    for (int kt = 0; kt < 4; ++kt) {
        f16x8 a[4], b[4];
        #pragma unroll
        for (int m = 0; m < 4; ++m)
            a[m] = *(const f16x8*)(ftile + (size_t)(rtA + m) * 2048 + kt * 512 + lo);
        #pragma unroll
        for (int n = 0; n < 4; ++n)
            b[n] = *(const f16x8*)(ftile + (size_t)(rtB + n) * 2048 + kt * 512 + lo);
        #pragma unroll
        for (int m = 0; m < 4; ++m)
            #pragma unroll
            for (int n = 0; n < 4; ++n)
                acc[m][n] = __builtin_amdgcn_mfma_f32_16x16x32_f16(b[n], a[m], acc[m][n], 0, 0, 0);
    }

    // epilogue. Output element (m,n,reg): i_loc = wr + m*16 + li (lane-const),
    // j_loc = wc + n*16 + g*4 + reg (same for all m).
    const bool diag = (!isProto) && (bi == bj);

    int clv[4][4];
    float wv[4][4];
    #pragma unroll
    for (int n = 0; n < 4; ++n) {
        int4 c4 = *(const int4*)&clab[wc + n * 16 + g * 4];
        clv[n][0] = c4.x; clv[n][1] = c4.y; clv[n][2] = c4.z; clv[n][3] = c4.w;
        if (isProto) {
            float4 w4 = *(const float4*)&cw[wc + n * 16 + g * 4];
            wv[n][0] = w4.x; wv[n][1] = w4.y; wv[n][2] = w4.z; wv[n][3] = w4.w;
        }
    }

    #pragma unroll
    for (int m = 0; m < 4; ++m) {
        const int i_loc = wr + m * 16 + li;
        const int rl = rlab[i_loc];
        float rn = 0.f, rd = 0.f;
        if (isProto) {
            #pragma unroll
            for (int n = 0; n < 4; ++n)
                #pragma unroll
                for (int r = 0; r < 4; ++r) {
                    float e = exp2f(acc[m][n][r]);
                    rd += e * wv[n][r];
                    if (clv[n][r] == rl) rn += e;
                }
        } else if (diag) {
            #pragma unroll
            for (int n = 0; n < 4; ++n)
                #pragma unroll
                for (int r = 0; r < 4; ++r) {
                    const int j_loc = wc + n * 16 + g * 4 + r;
                    float e = (i_loc == j_loc) ? 0.f : exp2f(acc[m][n][r]);
                    rd += e;
                    if (clv[n][r] == rl) rn += e;
                }
        } else {
            #pragma unroll
            for (int n = 0; n < 4; ++n)
                #pragma unroll
                for (int r = 0; r < 4; ++r) {
                    float e = exp2f(acc[m][n][r]);
                    rd += e;
                    if (clv[n][r] == rl) rn += e;
                }
        }
        rn += __shfl_xor(rn, 16, 64); rn += __shfl_xor(rn, 32, 64);
        rd += __shfl_xor(rd, 16, 64); rd += __shfl_xor(rd, 32, 64);
        if (lane < 16) {
            rowNs[w & 1][i_loc] = rn;
            rowDs[w & 1][i_loc] = rd;
        }
    }
    __syncthreads();
    if (t < 128) {
        atomicAdd(&numer[rowBase + t], rowNs[0][t] + rowNs[1][t]);
        float* dD = isProto ? denomP : denomR;
        atomicAdd(&dD[rowBase + t], rowDs[0][t] + rowDs[1][t]);
    }
}

// --- finalize: elementwise loss + mean --------------------------------------
__global__ void fin_kernel(const int* __restrict__ t2, const int* __restrict__ t3,
                           const float* __restrict__ cls_freq,
                           const float* __restrict__ numer,
                           const float* __restrict__ denomR,
                           const float* __restrict__ denomP,
                           float* loss_sum, int N, int M) {
    int i = blockIdx.x * blockDim.x + threadIdx.x;
    float loss = 0.f;
    if (i < M) {
        int lab = (i < N) ? t2[i] : t3[i - N];
        float denom = denomR[i] / cls_freq[lab] + denomP[i];
        loss = logf(denom + 1e-12f) - logf(numer[i]);
    }
    loss = wave_reduce_sum(loss);
    __shared__ float wsum[4];
    if ((threadIdx.x & 63) == 0) wsum[threadIdx.x >> 6] = loss;
    __syncthreads();
    if (threadIdx.x == 0)
        atomicAdd(loss_sum, wsum[0] + wsum[1] + wsum[2] + wsum[3]);
}

__global__ void out_kernel(const float* loss_sum, float* out, int M) {
    out[0] = loss_sum[0] / (float)M;
}

extern "C" void kernel_launch(void* const* d_in, const int* in_sizes, int n_in,
                              void* d_out, int out_size, void* d_ws, size_t ws_size,
                              hipStream_t stream) {
    const float* protos = (const float*)d_in[0];
    const float* proj2  = (const float*)d_in[1];
    const int*   t2     = (const int*)d_in[2];
    const float* proj3  = (const float*)d_in[3];
    const int*   t3     = (const int*)d_in[4];
    float* out = (float*)d_out;

    const int N = in_sizes[1] / D;   // 4096
    const int M = 2 * N;             // 8192
    const int MT = M + 128;

    _Float16* ftile = (_Float16*)d_ws;                        // MT * D halfs
    float* fbase    = (float*)(ftile + (size_t)MT * D);
    float* cls_freq = fbase;                                  // CCLS
    float* numer    = cls_freq + CCLS;                        // M
    float* denomR   = numer + M;                              // M
    float* denomP   = denomR + M;                             // M
    float* loss_sum = denomP + M;                             // 1

    init_kernel<<<(M + 255) / 256, 256, 0, stream>>>(numer, denomR, denomP,
                                                     loss_sum, M);
    hist_kernel<<<1, 1024, 0, stream>>>(t2, t3, cls_freq, N, M);
    norm_kernel<<<(MT + 3) / 4, 256, 0, stream>>>(protos, proj2, proj3, ftile, N, M);
    dim3 grid(M / 128, M / 128 + 1);
    sim_kernel<<<grid, 256, 0, stream>>>(ftile, t2, t3, cls_freq,
                                         numer, denomR, denomP, N, M);
    fin_kernel<<<(M + 255) / 256, 256, 0, stream>>>(t2, t3, cls_freq, numer,
                                                    denomR, denomP, loss_sum, N, M);
    out_kernel<<<1, 1, 0, stream>>>(loss_sum, out, M);
}